// Round 8
// baseline (238.262 us; speedup 1.0000x reference)
//
#include <hip/hip_runtime.h>
#include <stdint.h>

typedef unsigned short u16;
typedef short bf16x8 __attribute__((ext_vector_type(8)));
typedef short bf16x4 __attribute__((ext_vector_type(4)));
typedef float f32x4 __attribute__((ext_vector_type(4)));

#define MB (1u<<20)
#define CL2 0.18033688f   // log2(e)/sqrt(DK)

static __device__ __forceinline__ u16 f2bf(float x){
  union { float f; unsigned u; } v; v.f = x;
  return (u16)((v.u + 0x7FFFu + ((v.u >> 16) & 1u)) >> 16);
}

static __device__ __forceinline__ float bf2f(u16 x){
  union { unsigned u; float f; } v; v.u = ((unsigned)x) << 16;
  return v.f;
}

static __device__ __forceinline__ void gld_lds16(const void* g, void* l){
  __builtin_amdgcn_global_load_lds((const __attribute__((address_space(1))) unsigned int*)g,
                                   (__attribute__((address_space(3))) unsigned int*)l, 16, 0, 0);
}

// round-half-up f32 pair -> packed bf16x2 via v_perm (r4-verified; do NOT use
// v_cvt_pk_bf16_f32 here — r5 showed it breaks numerics on this toolchain).
static __device__ __forceinline__ int pack_bf16(float a, float b){
  unsigned ua = __float_as_uint(a) + 0x8000u;
  unsigned ub = __float_as_uint(b) + 0x8000u;
  return (int)__builtin_amdgcn_perm(ub, ua, 0x07060302u);
}

// ---------------- fp32 -> bf16 conversion of q,k,v ----------------
__global__ void convx(const float* __restrict__ q, const float* __restrict__ k, const float* __restrict__ v,
                      u16* __restrict__ qb, u16* __restrict__ kb, u16* __restrict__ vb){
  const float* s = blockIdx.z==0 ? q : (blockIdx.z==1 ? k : v);
  u16* d = blockIdx.z==0 ? qb : (blockIdx.z==1 ? kb : vb);
  int i = (blockIdx.x*256 + threadIdx.x)*4;
  float4 f = *(const float4*)(s + i);
  ushort4 o; o.x=f2bf(f.x); o.y=f2bf(f.y); o.z=f2bf(f.z); o.w=f2bf(f.w);
  *(ushort4*)(d + i) = o;
}

// ------------- weight transpose + convert: Wt[n][k] = bf16(W[k][n]) -------------
__global__ void convw(const float* W0,const float* W1,const float* W2,const float* W3,const float* W4,
                      u16* T0,u16* T1,u16* T2,u16* T3,u16* T4){
  const float* W = blockIdx.z==0?W0:blockIdx.z==1?W1:blockIdx.z==2?W2:blockIdx.z==3?W3:W4;
  u16* T = blockIdx.z==0?T0:blockIdx.z==1?T1:blockIdx.z==2?T2:blockIdx.z==3?T3:T4;
  __shared__ u16 t[64][65];
  int k0 = blockIdx.x*64, n0 = blockIdx.y*64;
  for (int i=0;i<16;i++){
    int idx = i*256 + threadIdx.x;
    int r = idx >> 6, c = idx & 63;
    t[r][c] = f2bf(W[(size_t)(k0+r)*1024 + n0 + c]);
  }
  __syncthreads();
  for (int i=0;i<2;i++){
    int idx = i*256 + threadIdx.x;
    int nl = idx >> 3, kc = idx & 7;
    bf16x8 o;
    #pragma unroll
    for (int j=0;j<8;j++) o[j] = (short)t[kc*8+j][nl];
    *(bf16x8*)(T + (size_t)(n0+nl)*1024 + k0 + kc*8) = o;
  }
}

// ---------------- 128x128 bf16 MFMA GEMM, B pre-transposed (Bt[n][k]) ----------------
// BK=64; LDS declared once at kernel scope and passed in (r3: per-instantiation
// __shared__ tripled LDS -> 1 block/CU). 3-bit XOR swizzle keeps ds_read_b128
// conflict-free. XCD-aware bijective block swizzle for L2 locality.
// MODE 0: bf16 row-major; 1: f32 row-major; 2: K attn layout; 3: V attn layout
// (x32-PV fragment order, see attn); 4: bf16 *CL2 (Q)
template<int MODE>
static __device__ __forceinline__ void gemm_bt_dev(u16* __restrict__ As, u16* __restrict__ Bs,
                                                   const u16* __restrict__ A, const u16* __restrict__ Bt,
                                                   const float* __restrict__ bias, void* __restrict__ Cout){
  const int tid = threadIdx.x, lane = tid & 63, w = tid >> 6;
  const int wm = w >> 1, wn = w & 1, quad = lane >> 4, lr = lane & 15;
  // bijective XCD swizzle over the 256 blocks of this z-slice (grid 8 x 32, nwg%8==0)
  const int fid = blockIdx.y * 8 + blockIdx.x;
  const int o   = (fid & 7) * 32 + (fid >> 3);
  const int n0  = (o & 7) * 128, m0 = (o >> 3) * 128;
  f32x4 acc[4][4] = {};
  const u16* Ab = A + (size_t)m0*1024;
  const u16* Bb = Bt + (size_t)n0*1024;
  // staging: 8 lanes per 128B row; issue j covers rows j*32 + w*8 .. +8
  const int srow_base = w*8 + (lane >> 3);
  const int sg = lane & 7;
  for (int k0 = 0; k0 < 1024; k0 += 64){
    #pragma unroll
    for (int j = 0; j < 4; ++j){
      int row = j*32 + srow_base;
      int g = sg ^ (row & 7);
      gld_lds16(Ab + (size_t)row*1024 + k0 + g*8, As + (j*32 + w*8)*64);
      gld_lds16(Bb + (size_t)row*1024 + k0 + g*8, Bs + (j*32 + w*8)*64);
    }
    __syncthreads();
    #pragma unroll
    for (int kk = 0; kk < 2; ++kk){
      bf16x8 af[4], bfr[4];
      #pragma unroll
      for (int i=0;i<4;i++){
        int ra = wm*64 + i*16 + lr;
        af[i]  = *(const bf16x8*)(As + ra*64 + (((kk*4+quad) ^ (ra & 7)))*8);
        int rb = wn*64 + i*16 + lr;
        bfr[i] = *(const bf16x8*)(Bs + rb*64 + (((kk*4+quad) ^ (rb & 7)))*8);
      }
      #pragma unroll
      for (int mi=0;mi<4;mi++)
        #pragma unroll
        for (int ni=0;ni<4;ni++)
          acc[mi][ni] = __builtin_amdgcn_mfma_f32_16x16x32_bf16(af[mi], bfr[ni], acc[mi][ni], 0, 0, 0);
    }
    __syncthreads();
  }
  #pragma unroll
  for (int mi=0;mi<4;mi++){
    int row = m0 + wm*64 + mi*16 + quad*4;
    #pragma unroll
    for (int ni=0;ni<4;ni++){
      int col = n0 + wn*64 + ni*16 + lr;
      float bb = bias[col];
      #pragma unroll
      for (int rg=0; rg<4; rg++){
        float vv = acc[mi][ni][rg] + bb;
        int r = row + rg;
        if (MODE == 0){
          ((u16*)Cout)[(size_t)r*1024 + col] = f2bf(vv);
        } else if (MODE == 4){
          ((u16*)Cout)[(size_t)r*1024 + col] = f2bf(vv * CL2);
        } else if (MODE == 1){
          ((float*)Cout)[(size_t)r*1024 + col] = vv;
        } else if (MODE == 2){
          // K: [bh][kb=16][hg=8][kvl=128][hl=8]
          int b2 = r >> 11, s = r & 2047, kb2 = s >> 7, kvl = s & 127;
          int hh = col >> 6, hg = (col & 63) >> 3, hl = col & 7;
          ((u16*)Cout)[((size_t)(b2*16+hh)*16 + kb2)*8192 + hg*1024 + kvl*8 + hl] = f2bf(vv);
        } else {
          // V for x32 PV: [bh][kb=16][mt2g=16][dd=64][j=8]
          // kv = 32*mt2 + 16*(j>>2) + 4*g + (j&3); elem = (mt2*4+g)*512 + dd*8 + j
          int b2 = r >> 11, s = r & 2047, kb2 = s >> 7, kvl = s & 127;
          int mt2v = kvl >> 5, gv = (kvl >> 2) & 3, jv = ((kvl >> 4) & 1)*4 + (kvl & 3);
          int hh = col >> 6, dd = col & 63;
          ((u16*)Cout)[((size_t)(b2*16+hh)*16 + kb2)*8192 + (size_t)(mt2v*4+gv)*512 + dd*8 + jv] = f2bf(vv);
        }
      }
    }
  }
}

__global__ void qkv_gemm(const u16* qb,const u16* kb,const u16* vb,
                         const u16* Wqt,const u16* Wkt,const u16* Wvt,
                         const float* bq,const float* bk,const float* bv,
                         u16* Qb,u16* Kr,u16* Vr){
  __shared__ u16 As[128*64];
  __shared__ u16 Bs[128*64];
  if (blockIdx.z == 0)      gemm_bt_dev<4>(As, Bs, qb, Wqt, bq, Qb);   // Q pre-scaled by CL2
  else if (blockIdx.z == 1) gemm_bt_dev<2>(As, Bs, kb, Wkt, bk, Kr);
  else                      gemm_bt_dev<3>(As, Bs, vb, Wvt, bv, Vr);
}

__global__ void out_gemm(const u16* Mg, const u16* Wct, const u16* Wot,
                         const float* bc, const float* bo, float* out){
  __shared__ u16 As[128*64];
  __shared__ u16 Bs[128*64];
  const u16* B = blockIdx.z==0? Wct : Wot;
  const float* bias = blockIdx.z==0? bc : bo;
  float* C = out + (blockIdx.z==0? 0 : 4194304);   // (c, h) concatenated
  gemm_bt_dev<1>(As, Bs, Mg, B, bias, C);
}

// ---------------- flash attention, transposed-score, no-max softmax ----------------
// r8: kv-split-2 for occupancy. r7 counters: no pipe >41% busy at 2 waves/SIMD
// (Occupancy 17%) -> latency-bound. Keeping 32-q waves (K/V frag reuse) and
// getting 4 blocks/CU forces kv-split=2: grid (16,32,2), each block owns 16
// kv-64 blocks; KVBLK 128->64 halves LDS to 32 KB (4 blocks/CU fit). Total LDS
// reads / staging / exp2 / MFMA counts are UNCHANGED vs r7 — only waves/SIMD
// doubles (2->4). Partials: O_h = (sum p*v)/l_h stored bf16 (same magnitude as
// final O) + l_h f32; attn_combine merges: O = (l0*O0 + l1*O1)/(l0+l1).
// Partials live in the dead qb/kb/vb workspace region (no new ws).
__global__ __launch_bounds__(256,4) void attn(const u16* __restrict__ Qb, const u16* __restrict__ Kr,
                                              const u16* __restrict__ Vr, u16* __restrict__ Opart,
                                              float* __restrict__ lpart){
  __shared__ u16 Ks[2][4096];
  __shared__ u16 Vs[2][4096];
  const int fid = blockIdx.y * 16 + blockIdx.x;        // 512 per z-slice, %8 == 0
  const int o   = (fid & 7) * 64 + (fid >> 3);
  const int qt = o & 15, bh = o >> 4, b = bh >> 4, h = bh & 15;
  const int kvh = blockIdx.z;
  const int tid = threadIdx.x, lane = tid & 63, w = tid >> 6;
  const int quad = lane >> 4, lr = lane & 15;
  const int q0 = qt*128 + w*32;

  bf16x8 aq[2][2];   // [q-subtile][ks]; Q pre-scaled by CL2
  #pragma unroll
  for (int t=0;t<2;t++)
    #pragma unroll
    for (int ks=0;ks<2;ks++)
      aq[t][ks] = *(const bf16x8*)(Qb + (size_t)(b*2048 + q0 + t*16 + lr)*1024 + h*64 + ks*32 + quad*8);

  f32x4 acco[2][4] = {};
  f32x4 accl[2] = {};
  const bf16x8 ones8 = {(short)0x3F80,(short)0x3F80,(short)0x3F80,(short)0x3F80,
                        (short)0x3F80,(short)0x3F80,(short)0x3F80,(short)0x3F80};

  const u16* Krb = Kr + (size_t)bh*131072;   // 16 kv128-blocks * 8192 elems
  const u16* Vrb = Vr + (size_t)bh*131072;

  // stage kv-64 block t (kb2 = t>>1, half = t&1) into buffer buf.
  // K: [hg=8][kvl=64][hl=8] (contig 512-elem chunk per hg); V: contig 4096-elem half.
  // per issue i: wave-uniform hg = i*4+w; lane covers kvl via lane*8.
  #define STAGE_KV(t_, buf_) do{                                                  \
    int kb2_ = (t_) >> 1, half_ = (t_) & 1;                                       \
    const u16* kg_ = Krb + (size_t)kb2_*8192 + half_*512;                         \
    const u16* vg_ = Vrb + (size_t)kb2_*8192 + half_*4096;                        \
    _Pragma("unroll")                                                             \
    for (int i_=0;i_<2;i_++){                                                     \
      gld_lds16(kg_ + (i_*4+w)*1024 + lane*8, &Ks[buf_][i_*2048 + w*512]);        \
      gld_lds16(vg_ + (i_*256 + w*64 + lane)*8, &Vs[buf_][i_*2048 + w*512]);      \
    }                                                                             \
  }while(0)

  STAGE_KV(kvh*16, 0);

  for (int it = 0; it < 16; it++){
    __syncthreads();                       // staged data for iteration it now visible
    const int cur = it & 1;
    if (it < 15) STAGE_KV(kvh*16 + it + 1, cur^1);
    const u16* Ksc = Ks[cur];
    const u16* Vsc = Vs[cur];

    // ---- per 32-kv pair of subtiles: QK -> exp/pack -> l -> PV, all native x32 ----
    #pragma unroll
    for (int mt2=0;mt2<2;mt2++){
      f32x4 ae0 = {}, ae1 = {}, ao0 = {}, ao1 = {};
      {
        bf16x8 kf0 = *(const bf16x8*)(Ksc + (0*4+quad)*512 + ((2*mt2)*16+lr)*8);
        bf16x8 kf1 = *(const bf16x8*)(Ksc + (1*4+quad)*512 + ((2*mt2)*16+lr)*8);
        ae0 = __builtin_amdgcn_mfma_f32_16x16x32_bf16(kf0, aq[0][0], ae0, 0,0,0);
        ae1 = __builtin_amdgcn_mfma_f32_16x16x32_bf16(kf0, aq[1][0], ae1, 0,0,0);
        ae0 = __builtin_amdgcn_mfma_f32_16x16x32_bf16(kf1, aq[0][1], ae0, 0,0,0);
        ae1 = __builtin_amdgcn_mfma_f32_16x16x32_bf16(kf1, aq[1][1], ae1, 0,0,0);
      }
      {
        bf16x8 kf0 = *(const bf16x8*)(Ksc + (0*4+quad)*512 + ((2*mt2+1)*16+lr)*8);
        bf16x8 kf1 = *(const bf16x8*)(Ksc + (1*4+quad)*512 + ((2*mt2+1)*16+lr)*8);
        ao0 = __builtin_amdgcn_mfma_f32_16x16x32_bf16(kf0, aq[0][0], ao0, 0,0,0);
        ao1 = __builtin_amdgcn_mfma_f32_16x16x32_bf16(kf0, aq[1][0], ao1, 0,0,0);
        ao0 = __builtin_amdgcn_mfma_f32_16x16x32_bf16(kf1, aq[0][1], ao0, 0,0,0);
        ao1 = __builtin_amdgcn_mfma_f32_16x16x32_bf16(kf1, aq[1][1], ao1, 0,0,0);
      }

      union { int4 i4; bf16x8 v; } pf0, pf1;
      pf0.i4.x = pack_bf16(__builtin_amdgcn_exp2f(ae0[0]), __builtin_amdgcn_exp2f(ae0[1]));
      pf0.i4.y = pack_bf16(__builtin_amdgcn_exp2f(ae0[2]), __builtin_amdgcn_exp2f(ae0[3]));
      pf0.i4.z = pack_bf16(__builtin_amdgcn_exp2f(ao0[0]), __builtin_amdgcn_exp2f(ao0[1]));
      pf0.i4.w = pack_bf16(__builtin_amdgcn_exp2f(ao0[2]), __builtin_amdgcn_exp2f(ao0[3]));
      pf1.i4.x = pack_bf16(__builtin_amdgcn_exp2f(ae1[0]), __builtin_amdgcn_exp2f(ae1[1]));
      pf1.i4.y = pack_bf16(__builtin_amdgcn_exp2f(ae1[2]), __builtin_amdgcn_exp2f(ae1[3]));
      pf1.i4.z = pack_bf16(__builtin_amdgcn_exp2f(ao1[0]), __builtin_amdgcn_exp2f(ao1[1]));
      pf1.i4.w = pack_bf16(__builtin_amdgcn_exp2f(ao1[2]), __builtin_amdgcn_exp2f(ao1[3]));

      accl[0] = __builtin_amdgcn_mfma_f32_16x16x32_bf16(ones8, pf0.v, accl[0], 0,0,0);
      accl[1] = __builtin_amdgcn_mfma_f32_16x16x32_bf16(ones8, pf1.v, accl[1], 0,0,0);

      #pragma unroll
      for (int dt=0;dt<4;dt++){
        bf16x8 vf = *(const bf16x8*)(Vsc + (mt2*4+quad)*512 + (dt*16+lr)*8);
        acco[0][dt] = __builtin_amdgcn_mfma_f32_16x16x32_bf16(vf, pf0.v, acco[0][dt], 0,0,0);
        acco[1][dt] = __builtin_amdgcn_mfma_f32_16x16x32_bf16(vf, pf1.v, acco[1][dt], 0,0,0);
      }
    }
  }
  #undef STAGE_KV

  // ---- epilogue: self-normalized bf16 partial O_h + f32 l_h ----
  u16* Oh = Opart + (size_t)kvh*4194304;         // [2][4096][1024] bf16
  float* lh = lpart + (size_t)kvh*65536;         // [2][4096][16]  f32
  #pragma unroll
  for (int t=0;t<2;t++){
    int r = b*2048 + q0 + t*16 + lr;
    float lv = accl[t][0];
    float inv = 1.f / lv;
    u16* dst = Oh + (size_t)r*1024 + h*64;
    #pragma unroll
    for (int dt=0;dt<4;dt++){
      bf16x4 o2;
      #pragma unroll
      for (int rg=0;rg<4;rg++) o2[rg] = (short)f2bf(acco[t][dt][rg]*inv);
      *(bf16x4*)(dst + dt*16 + quad*4) = o2;
    }
    if (quad == 0) lh[r*16 + h] = lv;
  }
}

// merge the two kv-half partials: O = (l0*O0 + l1*O1)/(l0+l1)
__global__ void attn_combine(const u16* __restrict__ Opart, const float* __restrict__ lpart,
                             u16* __restrict__ Mg){
  int r = blockIdx.x, c = threadIdx.x*4, h = threadIdx.x >> 4;
  float l0 = lpart[r*16 + h], l1 = lpart[65536 + r*16 + h];
  float w0 = l0 / (l0 + l1), w1 = 1.f - w0;
  bf16x4 x = *(const bf16x4*)(Opart + (size_t)r*1024 + c);
  bf16x4 y = *(const bf16x4*)(Opart + 4194304 + (size_t)r*1024 + c);
  bf16x4 o2;
  #pragma unroll
  for (int rg=0;rg<4;rg++)
    o2[rg] = (short)f2bf(w0*bf2f((u16)x[rg]) + w1*bf2f((u16)y[rg]));
  *(bf16x4*)(Mg + (size_t)r*1024 + c) = o2;
}

extern "C" void kernel_launch(void* const* d_in, const int* in_sizes, int n_in,
                              void* d_out, int out_size, void* d_ws, size_t ws_size,
                              hipStream_t stream){
  const float* q  = (const float*)d_in[0];
  const float* k  = (const float*)d_in[1];
  const float* v  = (const float*)d_in[2];
  const float* Wq = (const float*)d_in[3];
  const float* bq = (const float*)d_in[4];
  const float* Wk = (const float*)d_in[5];
  const float* bk = (const float*)d_in[6];
  const float* Wv = (const float*)d_in[7];
  const float* bv = (const float*)d_in[8];
  const float* Wo = (const float*)d_in[9];
  const float* bo = (const float*)d_in[10];
  const float* Wc = (const float*)d_in[11];
  const float* bc = (const float*)d_in[12];
  char* ws = (char*)d_ws;
  u16* qb  = (u16*)(ws + (size_t)0*MB);
  u16* kb  = (u16*)(ws + (size_t)8*MB);
  u16* vb  = (u16*)(ws + (size_t)16*MB);
  u16* Wqt = (u16*)(ws + (size_t)24*MB);
  u16* Wkt = (u16*)(ws + (size_t)26*MB);
  u16* Wvt = (u16*)(ws + (size_t)28*MB);
  u16* Wot = (u16*)(ws + (size_t)30*MB);
  u16* Wct = (u16*)(ws + (size_t)32*MB);
  u16* Qb  = (u16*)(ws + (size_t)34*MB);
  u16* Kr  = (u16*)(ws + (size_t)42*MB);
  u16* Vr  = (u16*)(ws + (size_t)50*MB);
  u16* Mg  = (u16*)(ws + (size_t)58*MB);
  // attn partials reuse the qb/kb/vb region (dead after qkv_gemm):
  u16*  Opart = (u16*)(ws + (size_t)0*MB);     // [2][4096][1024] bf16 = 16 MB
  float* lpart = (float*)(ws + (size_t)16*MB); // [2][4096][16]  f32 = 512 KB

  dim3 blk(256,1,1);
  hipLaunchKernelGGL(convx,    dim3(4096,1,3), blk, 0, stream, q,k,v, qb,kb,vb);
  hipLaunchKernelGGL(convw,    dim3(16,16,5),  blk, 0, stream, Wq,Wk,Wv,Wo,Wc, Wqt,Wkt,Wvt,Wot,Wct);
  hipLaunchKernelGGL(qkv_gemm, dim3(8,32,3),   blk, 0, stream, qb,kb,vb, Wqt,Wkt,Wvt, bq,bk,bv, Qb,Kr,Vr);
  hipLaunchKernelGGL(attn,     dim3(16,32,2),  blk, 0, stream, Qb, Kr, Vr, Opart, lpart);
  hipLaunchKernelGGL(attn_combine, dim3(4096,1,1), blk, 0, stream, Opart, lpart, Mg);
  hipLaunchKernelGGL(out_gemm, dim3(8,32,2),   blk, 0, stream, Mg, Wct, Wot, bc, bo, (float*)d_out);
}

// Round 9
// 221.849 us; speedup vs baseline: 1.0740x; 1.0740x over previous
//
#include <hip/hip_runtime.h>
#include <stdint.h>

typedef unsigned short u16;
typedef short bf16x8 __attribute__((ext_vector_type(8)));
typedef short bf16x4 __attribute__((ext_vector_type(4)));
typedef float f32x4 __attribute__((ext_vector_type(4)));

#define MB (1u<<20)
#define CL2 0.18033688f   // log2(e)/sqrt(DK)

static __device__ __forceinline__ u16 f2bf(float x){
  union { float f; unsigned u; } v; v.f = x;
  return (u16)((v.u + 0x7FFFu + ((v.u >> 16) & 1u)) >> 16);
}

static __device__ __forceinline__ void gld_lds16(const void* g, void* l){
  __builtin_amdgcn_global_load_lds((const __attribute__((address_space(1))) unsigned int*)g,
                                   (__attribute__((address_space(3))) unsigned int*)l, 16, 0, 0);
}

// round-half-up f32 pair -> packed bf16x2 via v_perm (r4-verified; do NOT use
// v_cvt_pk_bf16_f32 here — r5 showed it breaks numerics on this toolchain).
static __device__ __forceinline__ int pack_bf16(float a, float b){
  unsigned ua = __float_as_uint(a) + 0x8000u;
  unsigned ub = __float_as_uint(b) + 0x8000u;
  return (int)__builtin_amdgcn_perm(ub, ua, 0x07060302u);
}

// ------------- fused prologue: qkv f32->bf16 (z<3) + weight transpose (z==3) -------------
// r9: one launch instead of two (launch-gap probe; convx/convw are independent).
__global__ void conv_all(const float* __restrict__ q, const float* __restrict__ k, const float* __restrict__ v,
                         u16* __restrict__ qb, u16* __restrict__ kb, u16* __restrict__ vb,
                         const float* W0,const float* W1,const float* W2,const float* W3,const float* W4,
                         u16* T0,u16* T1,u16* T2,u16* T3,u16* T4){
  __shared__ u16 t[64][65];
  if (blockIdx.z < 3){
    const float* s = blockIdx.z==0 ? q : (blockIdx.z==1 ? k : v);
    u16* d = blockIdx.z==0 ? qb : (blockIdx.z==1 ? kb : vb);
    int i = (blockIdx.x*256 + threadIdx.x)*4;
    float4 f = *(const float4*)(s + i);
    ushort4 o; o.x=f2bf(f.x); o.y=f2bf(f.y); o.z=f2bf(f.z); o.w=f2bf(f.w);
    *(ushort4*)(d + i) = o;
    return;
  }
  if (blockIdx.x >= 1280) return;          // 5 weights x 256 tiles
  const int wsel = blockIdx.x >> 8;
  const float* W = wsel==0?W0:wsel==1?W1:wsel==2?W2:wsel==3?W3:W4;
  u16* T = wsel==0?T0:wsel==1?T1:wsel==2?T2:wsel==3?T3:T4;
  const int idx2 = blockIdx.x & 255;
  int k0 = (idx2 & 15)*64, n0 = (idx2 >> 4)*64;
  for (int i=0;i<16;i++){
    int idx = i*256 + threadIdx.x;
    int r = idx >> 6, c = idx & 63;
    t[r][c] = f2bf(W[(size_t)(k0+r)*1024 + n0 + c]);
  }
  __syncthreads();
  for (int i=0;i<2;i++){
    int idx = i*256 + threadIdx.x;
    int nl = idx >> 3, kc = idx & 7;
    bf16x8 o;
    #pragma unroll
    for (int j=0;j<8;j++) o[j] = (short)t[kc*8+j][nl];
    *(bf16x8*)(T + (size_t)(n0+nl)*1024 + k0 + kc*8) = o;
  }
}

// ---------------- 128x128 bf16 MFMA GEMM, B pre-transposed (Bt[n][k]) ----------------
// BK=64; LDS declared once at kernel scope and passed in (r3: per-instantiation
// __shared__ tripled LDS -> 1 block/CU). 3-bit XOR swizzle keeps ds_read_b128
// conflict-free. XCD-aware bijective block swizzle for L2 locality.
// MODE 0: bf16 row-major; 1: f32 row-major; 2: K attn layout; 3: V attn layout
// (x32-PV fragment order, see attn); 4: bf16 *CL2 (Q)
template<int MODE>
static __device__ __forceinline__ void gemm_bt_dev(u16* __restrict__ As, u16* __restrict__ Bs,
                                                   const u16* __restrict__ A, const u16* __restrict__ Bt,
                                                   const float* __restrict__ bias, void* __restrict__ Cout){
  const int tid = threadIdx.x, lane = tid & 63, w = tid >> 6;
  const int wm = w >> 1, wn = w & 1, quad = lane >> 4, lr = lane & 15;
  // bijective XCD swizzle over the 256 blocks of this z-slice (grid 8 x 32, nwg%8==0)
  const int fid = blockIdx.y * 8 + blockIdx.x;
  const int o   = (fid & 7) * 32 + (fid >> 3);
  const int n0  = (o & 7) * 128, m0 = (o >> 3) * 128;
  f32x4 acc[4][4] = {};
  const u16* Ab = A + (size_t)m0*1024;
  const u16* Bb = Bt + (size_t)n0*1024;
  // staging: 8 lanes per 128B row; issue j covers rows j*32 + w*8 .. +8
  const int srow_base = w*8 + (lane >> 3);
  const int sg = lane & 7;
  for (int k0 = 0; k0 < 1024; k0 += 64){
    #pragma unroll
    for (int j = 0; j < 4; ++j){
      int row = j*32 + srow_base;
      int g = sg ^ (row & 7);
      gld_lds16(Ab + (size_t)row*1024 + k0 + g*8, As + (j*32 + w*8)*64);
      gld_lds16(Bb + (size_t)row*1024 + k0 + g*8, Bs + (j*32 + w*8)*64);
    }
    __syncthreads();
    #pragma unroll
    for (int kk = 0; kk < 2; ++kk){
      bf16x8 af[4], bfr[4];
      #pragma unroll
      for (int i=0;i<4;i++){
        int ra = wm*64 + i*16 + lr;
        af[i]  = *(const bf16x8*)(As + ra*64 + (((kk*4+quad) ^ (ra & 7)))*8);
        int rb = wn*64 + i*16 + lr;
        bfr[i] = *(const bf16x8*)(Bs + rb*64 + (((kk*4+quad) ^ (rb & 7)))*8);
      }
      #pragma unroll
      for (int mi=0;mi<4;mi++)
        #pragma unroll
        for (int ni=0;ni<4;ni++)
          acc[mi][ni] = __builtin_amdgcn_mfma_f32_16x16x32_bf16(af[mi], bfr[ni], acc[mi][ni], 0, 0, 0);
    }
    __syncthreads();
  }
  #pragma unroll
  for (int mi=0;mi<4;mi++){
    int row = m0 + wm*64 + mi*16 + quad*4;
    #pragma unroll
    for (int ni=0;ni<4;ni++){
      int col = n0 + wn*64 + ni*16 + lr;
      float bb = bias[col];
      #pragma unroll
      for (int rg=0; rg<4; rg++){
        float vv = acc[mi][ni][rg] + bb;
        int r = row + rg;
        if (MODE == 0){
          ((u16*)Cout)[(size_t)r*1024 + col] = f2bf(vv);
        } else if (MODE == 4){
          ((u16*)Cout)[(size_t)r*1024 + col] = f2bf(vv * CL2);
        } else if (MODE == 1){
          ((float*)Cout)[(size_t)r*1024 + col] = vv;
        } else if (MODE == 2){
          // K: [bh][kb=16][hg=8][kvl=128][hl=8]
          int b2 = r >> 11, s = r & 2047, kb2 = s >> 7, kvl = s & 127;
          int hh = col >> 6, hg = (col & 63) >> 3, hl = col & 7;
          ((u16*)Cout)[((size_t)(b2*16+hh)*16 + kb2)*8192 + hg*1024 + kvl*8 + hl] = f2bf(vv);
        } else {
          // V for x32 PV: [bh][kb=16][mt2g=16][dd=64][j=8]
          // kv = 32*mt2 + 16*(j>>2) + 4*g + (j&3); elem = (mt2*4+g)*512 + dd*8 + j
          int b2 = r >> 11, s = r & 2047, kb2 = s >> 7, kvl = s & 127;
          int mt2v = kvl >> 5, gv = (kvl >> 2) & 3, jv = ((kvl >> 4) & 1)*4 + (kvl & 3);
          int hh = col >> 6, dd = col & 63;
          ((u16*)Cout)[((size_t)(b2*16+hh)*16 + kb2)*8192 + (size_t)(mt2v*4+gv)*512 + dd*8 + jv] = f2bf(vv);
        }
      }
    }
  }
}

__global__ void qkv_gemm(const u16* qb,const u16* kb,const u16* vb,
                         const u16* Wqt,const u16* Wkt,const u16* Wvt,
                         const float* bq,const float* bk,const float* bv,
                         u16* Qb,u16* Kr,u16* Vr){
  __shared__ u16 As[128*64];
  __shared__ u16 Bs[128*64];
  if (blockIdx.z == 0)      gemm_bt_dev<4>(As, Bs, qb, Wqt, bq, Qb);   // Q pre-scaled by CL2
  else if (blockIdx.z == 1) gemm_bt_dev<2>(As, Bs, kb, Wkt, bk, Kr);
  else                      gemm_bt_dev<3>(As, Bs, vb, Wvt, bv, Vr);
}

__global__ void out_gemm(const u16* Mg, const u16* Wct, const u16* Wot,
                         const float* bc, const float* bo, float* out){
  __shared__ u16 As[128*64];
  __shared__ u16 Bs[128*64];
  const u16* B = blockIdx.z==0? Wct : Wot;
  const float* bias = blockIdx.z==0? bc : bo;
  float* C = out + (blockIdx.z==0? 0 : 4194304);   // (c, h) concatenated
  gemm_bt_dev<1>(As, Bs, Mg, B, bias, C);
}

// ---------------- flash attention, transposed-score, no-max softmax ----------------
// r9 = r7 verbatim (best measured attn: 45.8 us). r8's kv-split (4 blocks/CU)
// proved occupancy is NOT the binding constraint (zero speedup at 2x waves/SIMD):
// all waves stall at the same per-iter barrier + serial QK->exp2->pack->PV chain.
// block = 256 threads (4 waves); each wave owns 32 q; KV-block = 128; dbuf LDS 64KB;
// PV/l on native 16x16x32 via pre-permuted V (MODE-3 epilogue), zero shuffles.
// XCD swizzle: the 16 q-blocks sharing one bh's K/V colocate on one XCD.
__global__ __launch_bounds__(256,2) void attn(const u16* __restrict__ Qb, const u16* __restrict__ Kr,
                                              const u16* __restrict__ Vr, u16* __restrict__ Mg){
  __shared__ u16 Ks[2][8192];
  __shared__ u16 Vs[2][8192];
  const int fid = blockIdx.y * 16 + blockIdx.x;        // nwg = 512, %8 == 0
  const int o   = (fid & 7) * 64 + (fid >> 3);
  const int qt = o & 15, bh = o >> 4, b = bh >> 4, h = bh & 15;
  const int tid = threadIdx.x, lane = tid & 63, w = tid >> 6;
  const int quad = lane >> 4, lr = lane & 15;
  const int q0 = qt*128 + w*32;

  bf16x8 aq[2][2];   // [q-subtile][ks]; Q pre-scaled by CL2
  #pragma unroll
  for (int t=0;t<2;t++)
    #pragma unroll
    for (int ks=0;ks<2;ks++)
      aq[t][ks] = *(const bf16x8*)(Qb + (size_t)(b*2048 + q0 + t*16 + lr)*1024 + h*64 + ks*32 + quad*8);

  f32x4 acco[2][4] = {};
  f32x4 accl[2] = {};
  const bf16x8 ones8 = {(short)0x3F80,(short)0x3F80,(short)0x3F80,(short)0x3F80,
                        (short)0x3F80,(short)0x3F80,(short)0x3F80,(short)0x3F80};

  const u16* Krb = Kr + (size_t)bh*131072;   // 16 kv-blocks * 8192 elems
  const u16* Vrb = Vr + (size_t)bh*131072;

  // prefetch kv-block 0 (4 chunks of 4 KB each per buffer)
  #pragma unroll
  for (int j=0;j<4;j++){
    gld_lds16(Krb + j*2048 + tid*8, &Ks[0][j*2048 + w*512]);
    gld_lds16(Vrb + j*2048 + tid*8, &Vs[0][j*2048 + w*512]);
  }

  for (int kb = 0; kb < 16; kb++){
    __syncthreads();                       // staged data for kb now visible
    const int cur = kb & 1;
    if (kb < 15){
      const u16* kg = Krb + (size_t)(kb+1)*8192;
      const u16* vg = Vrb + (size_t)(kb+1)*8192;
      #pragma unroll
      for (int j=0;j<4;j++){
        gld_lds16(kg + j*2048 + tid*8, &Ks[cur^1][j*2048 + w*512]);
        gld_lds16(vg + j*2048 + tid*8, &Vs[cur^1][j*2048 + w*512]);
      }
    }
    const u16* Ksc = Ks[cur];
    const u16* Vsc = Vs[cur];

    // ---- per 32-kv pair of subtiles: QK -> exp/pack -> l -> PV, all native x32 ----
    #pragma unroll
    for (int mt2=0;mt2<4;mt2++){
      f32x4 ae0 = {}, ae1 = {}, ao0 = {}, ao1 = {};
      {
        bf16x8 kf0 = *(const bf16x8*)(Ksc + (0*4+quad)*1024 + ((2*mt2)*16+lr)*8);
        bf16x8 kf1 = *(const bf16x8*)(Ksc + (1*4+quad)*1024 + ((2*mt2)*16+lr)*8);
        ae0 = __builtin_amdgcn_mfma_f32_16x16x32_bf16(kf0, aq[0][0], ae0, 0,0,0);
        ae1 = __builtin_amdgcn_mfma_f32_16x16x32_bf16(kf0, aq[1][0], ae1, 0,0,0);
        ae0 = __builtin_amdgcn_mfma_f32_16x16x32_bf16(kf1, aq[0][1], ae0, 0,0,0);
        ae1 = __builtin_amdgcn_mfma_f32_16x16x32_bf16(kf1, aq[1][1], ae1, 0,0,0);
      }
      {
        bf16x8 kf0 = *(const bf16x8*)(Ksc + (0*4+quad)*1024 + ((2*mt2+1)*16+lr)*8);
        bf16x8 kf1 = *(const bf16x8*)(Ksc + (1*4+quad)*1024 + ((2*mt2+1)*16+lr)*8);
        ao0 = __builtin_amdgcn_mfma_f32_16x16x32_bf16(kf0, aq[0][0], ao0, 0,0,0);
        ao1 = __builtin_amdgcn_mfma_f32_16x16x32_bf16(kf0, aq[1][0], ao1, 0,0,0);
        ao0 = __builtin_amdgcn_mfma_f32_16x16x32_bf16(kf1, aq[0][1], ao0, 0,0,0);
        ao1 = __builtin_amdgcn_mfma_f32_16x16x32_bf16(kf1, aq[1][1], ao1, 0,0,0);
      }

      // p = exp2(s'); pack even-mt into elems 0..3, odd-mt into 4..7 (x32 B-frag order)
      union { int4 i4; bf16x8 v; } pf0, pf1;
      pf0.i4.x = pack_bf16(__builtin_amdgcn_exp2f(ae0[0]), __builtin_amdgcn_exp2f(ae0[1]));
      pf0.i4.y = pack_bf16(__builtin_amdgcn_exp2f(ae0[2]), __builtin_amdgcn_exp2f(ae0[3]));
      pf0.i4.z = pack_bf16(__builtin_amdgcn_exp2f(ao0[0]), __builtin_amdgcn_exp2f(ao0[1]));
      pf0.i4.w = pack_bf16(__builtin_amdgcn_exp2f(ao0[2]), __builtin_amdgcn_exp2f(ao0[3]));
      pf1.i4.x = pack_bf16(__builtin_amdgcn_exp2f(ae1[0]), __builtin_amdgcn_exp2f(ae1[1]));
      pf1.i4.y = pack_bf16(__builtin_amdgcn_exp2f(ae1[2]), __builtin_amdgcn_exp2f(ae1[3]));
      pf1.i4.z = pack_bf16(__builtin_amdgcn_exp2f(ao1[0]), __builtin_amdgcn_exp2f(ao1[1]));
      pf1.i4.w = pack_bf16(__builtin_amdgcn_exp2f(ao1[2]), __builtin_amdgcn_exp2f(ao1[3]));

      // l via native x32: every C row = sum over this 32-kv chunk
      accl[0] = __builtin_amdgcn_mfma_f32_16x16x32_bf16(ones8, pf0.v, accl[0], 0,0,0);
      accl[1] = __builtin_amdgcn_mfma_f32_16x16x32_bf16(ones8, pf1.v, accl[1], 0,0,0);

      // O^T += V^T * P^T (32 kv per op; vf read feeds both q-subtiles)
      #pragma unroll
      for (int dt=0;dt<4;dt++){
        bf16x8 vf = *(const bf16x8*)(Vsc + (mt2*4+quad)*512 + (dt*16+lr)*8);
        acco[0][dt] = __builtin_amdgcn_mfma_f32_16x16x32_bf16(vf, pf0.v, acco[0][dt], 0,0,0);
        acco[1][dt] = __builtin_amdgcn_mfma_f32_16x16x32_bf16(vf, pf1.v, acco[1][dt], 0,0,0);
      }
    }
  }

  // ---- epilogue: accl rows are all identical = l(q=lane&15); lane-local ----
  #pragma unroll
  for (int t=0;t<2;t++){
    float inv = 1.f / accl[t][0];
    u16* dst = Mg + (size_t)(b*2048 + q0 + t*16 + lr)*1024 + h*64;
    #pragma unroll
    for (int dt=0;dt<4;dt++){
      bf16x4 o2;
      #pragma unroll
      for (int rg=0;rg<4;rg++) o2[rg] = (short)f2bf(acco[t][dt][rg]*inv);
      *(bf16x4*)(dst + dt*16 + quad*4) = o2;
    }
  }
}

extern "C" void kernel_launch(void* const* d_in, const int* in_sizes, int n_in,
                              void* d_out, int out_size, void* d_ws, size_t ws_size,
                              hipStream_t stream){
  const float* q  = (const float*)d_in[0];
  const float* k  = (const float*)d_in[1];
  const float* v  = (const float*)d_in[2];
  const float* Wq = (const float*)d_in[3];
  const float* bq = (const float*)d_in[4];
  const float* Wk = (const float*)d_in[5];
  const float* bk = (const float*)d_in[6];
  const float* Wv = (const float*)d_in[7];
  const float* bv = (const float*)d_in[8];
  const float* Wo = (const float*)d_in[9];
  const float* bo = (const float*)d_in[10];
  const float* Wc = (const float*)d_in[11];
  const float* bc = (const float*)d_in[12];
  char* ws = (char*)d_ws;
  u16* qb  = (u16*)(ws + (size_t)0*MB);
  u16* kb  = (u16*)(ws + (size_t)8*MB);
  u16* vb  = (u16*)(ws + (size_t)16*MB);
  u16* Wqt = (u16*)(ws + (size_t)24*MB);
  u16* Wkt = (u16*)(ws + (size_t)26*MB);
  u16* Wvt = (u16*)(ws + (size_t)28*MB);
  u16* Wot = (u16*)(ws + (size_t)30*MB);
  u16* Wct = (u16*)(ws + (size_t)32*MB);
  u16* Qb  = (u16*)(ws + (size_t)34*MB);
  u16* Kr  = (u16*)(ws + (size_t)42*MB);
  u16* Vr  = (u16*)(ws + (size_t)50*MB);
  u16* Mg  = (u16*)(ws + (size_t)58*MB);

  dim3 blk(256,1,1);
  hipLaunchKernelGGL(conv_all, dim3(4096,1,4), blk, 0, stream,
                     q,k,v, qb,kb,vb, Wq,Wk,Wv,Wo,Wc, Wqt,Wkt,Wvt,Wot,Wct);
  hipLaunchKernelGGL(qkv_gemm, dim3(8,32,3),   blk, 0, stream, qb,kb,vb, Wqt,Wkt,Wvt, bq,bk,bv, Qb,Kr,Vr);
  hipLaunchKernelGGL(attn,     dim3(16,32,1),  blk, 0, stream, Qb, Kr, Vr, Mg);
  hipLaunchKernelGGL(out_gemm, dim3(8,32,2),   blk, 0, stream, Mg, Wct, Wot, bc, bo, (float*)d_out);
}

// Round 10
// 220.323 us; speedup vs baseline: 1.0814x; 1.0069x over previous
//
#include <hip/hip_runtime.h>
#include <stdint.h>

typedef unsigned short u16;
typedef short bf16x8 __attribute__((ext_vector_type(8)));
typedef short bf16x4 __attribute__((ext_vector_type(4)));
typedef float f32x4 __attribute__((ext_vector_type(4)));

#define MB (1u<<20)
#define CL2 0.18033688f   // log2(e)/sqrt(DK)

static __device__ __forceinline__ u16 f2bf(float x){
  union { float f; unsigned u; } v; v.f = x;
  return (u16)((v.u + 0x7FFFu + ((v.u >> 16) & 1u)) >> 16);
}

static __device__ __forceinline__ void gld_lds16(const void* g, void* l){
  __builtin_amdgcn_global_load_lds((const __attribute__((address_space(1))) unsigned int*)g,
                                   (__attribute__((address_space(3))) unsigned int*)l, 16, 0, 0);
}

// round-half-up f32 pair -> packed bf16x2 via v_perm (r4-verified; do NOT use
// v_cvt_pk_bf16_f32 here — r5 showed it breaks numerics on this toolchain).
static __device__ __forceinline__ int pack_bf16(float a, float b){
  unsigned ua = __float_as_uint(a) + 0x8000u;
  unsigned ub = __float_as_uint(b) + 0x8000u;
  return (int)__builtin_amdgcn_perm(ub, ua, 0x07060302u);
}

// ------------- fused prologue: qkv f32->bf16 (z<3) + weight transpose (z==3) -------------
__global__ void conv_all(const float* __restrict__ q, const float* __restrict__ k, const float* __restrict__ v,
                         u16* __restrict__ qb, u16* __restrict__ kb, u16* __restrict__ vb,
                         const float* W0,const float* W1,const float* W2,const float* W3,const float* W4,
                         u16* T0,u16* T1,u16* T2,u16* T3,u16* T4){
  __shared__ u16 t[64][65];
  if (blockIdx.z < 3){
    const float* s = blockIdx.z==0 ? q : (blockIdx.z==1 ? k : v);
    u16* d = blockIdx.z==0 ? qb : (blockIdx.z==1 ? kb : vb);
    int i = (blockIdx.x*256 + threadIdx.x)*4;
    float4 f = *(const float4*)(s + i);
    ushort4 o; o.x=f2bf(f.x); o.y=f2bf(f.y); o.z=f2bf(f.z); o.w=f2bf(f.w);
    *(ushort4*)(d + i) = o;
    return;
  }
  if (blockIdx.x >= 1280) return;          // 5 weights x 256 tiles
  const int wsel = blockIdx.x >> 8;
  const float* W = wsel==0?W0:wsel==1?W1:wsel==2?W2:wsel==3?W3:W4;
  u16* T = wsel==0?T0:wsel==1?T1:wsel==2?T2:wsel==3?T3:T4;
  const int idx2 = blockIdx.x & 255;
  int k0 = (idx2 & 15)*64, n0 = (idx2 >> 4)*64;
  for (int i=0;i<16;i++){
    int idx = i*256 + threadIdx.x;
    int r = idx >> 6, c = idx & 63;
    t[r][c] = f2bf(W[(size_t)(k0+r)*1024 + n0 + c]);
  }
  __syncthreads();
  for (int i=0;i<2;i++){
    int idx = i*256 + threadIdx.x;
    int nl = idx >> 3, kc = idx & 7;
    bf16x8 o;
    #pragma unroll
    for (int j=0;j<8;j++) o[j] = (short)t[kc*8+j][nl];
    *(bf16x8*)(T + (size_t)(n0+nl)*1024 + k0 + kc*8) = o;
  }
}

// ---------------- 128x128 bf16 MFMA GEMM, B pre-transposed (Bt[n][k]) ----------------
// BK=64; LDS declared once at kernel scope and passed in (r3: per-instantiation
// __shared__ tripled LDS -> 1 block/CU). 3-bit XOR swizzle keeps ds_read_b128
// conflict-free. XCD-aware bijective block swizzle for L2 locality.
// MODE 0: bf16 row-major; 1: f32 row-major; 2: K attn layout; 3: V attn layout
// (x32-PV fragment order, see attn); 4: bf16 *CL2 (Q)
template<int MODE>
static __device__ __forceinline__ void gemm_bt_dev(u16* __restrict__ As, u16* __restrict__ Bs,
                                                   const u16* __restrict__ A, const u16* __restrict__ Bt,
                                                   const float* __restrict__ bias, void* __restrict__ Cout){
  const int tid = threadIdx.x, lane = tid & 63, w = tid >> 6;
  const int wm = w >> 1, wn = w & 1, quad = lane >> 4, lr = lane & 15;
  // bijective XCD swizzle over the 256 blocks of this z-slice (grid 8 x 32, nwg%8==0)
  const int fid = blockIdx.y * 8 + blockIdx.x;
  const int o   = (fid & 7) * 32 + (fid >> 3);
  const int n0  = (o & 7) * 128, m0 = (o >> 3) * 128;
  f32x4 acc[4][4] = {};
  const u16* Ab = A + (size_t)m0*1024;
  const u16* Bb = Bt + (size_t)n0*1024;
  // staging: 8 lanes per 128B row; issue j covers rows j*32 + w*8 .. +8
  const int srow_base = w*8 + (lane >> 3);
  const int sg = lane & 7;
  for (int k0 = 0; k0 < 1024; k0 += 64){
    #pragma unroll
    for (int j = 0; j < 4; ++j){
      int row = j*32 + srow_base;
      int g = sg ^ (row & 7);
      gld_lds16(Ab + (size_t)row*1024 + k0 + g*8, As + (j*32 + w*8)*64);
      gld_lds16(Bb + (size_t)row*1024 + k0 + g*8, Bs + (j*32 + w*8)*64);
    }
    __syncthreads();
    #pragma unroll
    for (int kk = 0; kk < 2; ++kk){
      bf16x8 af[4], bfr[4];
      #pragma unroll
      for (int i=0;i<4;i++){
        int ra = wm*64 + i*16 + lr;
        af[i]  = *(const bf16x8*)(As + ra*64 + (((kk*4+quad) ^ (ra & 7)))*8);
        int rb = wn*64 + i*16 + lr;
        bfr[i] = *(const bf16x8*)(Bs + rb*64 + (((kk*4+quad) ^ (rb & 7)))*8);
      }
      #pragma unroll
      for (int mi=0;mi<4;mi++)
        #pragma unroll
        for (int ni=0;ni<4;ni++)
          acc[mi][ni] = __builtin_amdgcn_mfma_f32_16x16x32_bf16(af[mi], bfr[ni], acc[mi][ni], 0, 0, 0);
    }
    __syncthreads();
  }
  #pragma unroll
  for (int mi=0;mi<4;mi++){
    int row = m0 + wm*64 + mi*16 + quad*4;
    #pragma unroll
    for (int ni=0;ni<4;ni++){
      int col = n0 + wn*64 + ni*16 + lr;
      float bb = bias[col];
      #pragma unroll
      for (int rg=0; rg<4; rg++){
        float vv = acc[mi][ni][rg] + bb;
        int r = row + rg;
        if (MODE == 0){
          ((u16*)Cout)[(size_t)r*1024 + col] = f2bf(vv);
        } else if (MODE == 4){
          ((u16*)Cout)[(size_t)r*1024 + col] = f2bf(vv * CL2);
        } else if (MODE == 1){
          ((float*)Cout)[(size_t)r*1024 + col] = vv;
        } else if (MODE == 2){
          // K: [bh][kb=16][hg=8][kvl=128][hl=8]
          int b2 = r >> 11, s = r & 2047, kb2 = s >> 7, kvl = s & 127;
          int hh = col >> 6, hg = (col & 63) >> 3, hl = col & 7;
          ((u16*)Cout)[((size_t)(b2*16+hh)*16 + kb2)*8192 + hg*1024 + kvl*8 + hl] = f2bf(vv);
        } else {
          // V for x32 PV: [bh][kb=16][mt2g=16][dd=64][j=8]
          // kv = 32*mt2 + 16*(j>>2) + 4*g + (j&3); elem = (mt2*4+g)*512 + dd*8 + j
          int b2 = r >> 11, s = r & 2047, kb2 = s >> 7, kvl = s & 127;
          int mt2v = kvl >> 5, gv = (kvl >> 2) & 3, jv = ((kvl >> 4) & 1)*4 + (kvl & 3);
          int hh = col >> 6, dd = col & 63;
          ((u16*)Cout)[((size_t)(b2*16+hh)*16 + kb2)*8192 + (size_t)(mt2v*4+gv)*512 + dd*8 + jv] = f2bf(vv);
        }
      }
    }
  }
}

__global__ void qkv_gemm(const u16* qb,const u16* kb,const u16* vb,
                         const u16* Wqt,const u16* Wkt,const u16* Wvt,
                         const float* bq,const float* bk,const float* bv,
                         u16* Qb,u16* Kr,u16* Vr){
  __shared__ u16 As[128*64];
  __shared__ u16 Bs[128*64];
  if (blockIdx.z == 0)      gemm_bt_dev<4>(As, Bs, qb, Wqt, bq, Qb);   // Q pre-scaled by CL2
  else if (blockIdx.z == 1) gemm_bt_dev<2>(As, Bs, kb, Wkt, bk, Kr);
  else                      gemm_bt_dev<3>(As, Bs, vb, Wvt, bv, Vr);
}

__global__ void out_gemm(const u16* Mg, const u16* Wct, const u16* Wot,
                         const float* bc, const float* bo, float* out){
  __shared__ u16 As[128*64];
  __shared__ u16 Bs[128*64];
  const u16* B = blockIdx.z==0? Wct : Wot;
  const float* bias = blockIdx.z==0? bc : bo;
  float* C = out + (blockIdx.z==0? 0 : 4194304);   // (c, h) concatenated
  gemm_bt_dev<1>(As, Bs, Mg, B, bias, C);
}

// ---------------- flash attention, transposed-score, no-max softmax ----------------
// r10: QBLK=256 (512 threads / 8 waves), KVBLK=128 unchanged. Each staged K/V
// tile now feeds 8 waves (was 4): staging bytes per FLOP halve, barrier events
// per q-row halve, LDS stays 64 KB. Grid 256 blocks = 1/CU (same 2 waves/SIMD
// as r7 — r8 proved raw occupancy is not the lever; per-iteration structural
// overhead is the theory under test). PV/l on native 16x16x32 via pre-permuted V.
// XCD swizzle: 8 qt-blocks of one bh colocate; 4 bh per XCD (2 MB L2-resident).
__global__ __launch_bounds__(512,1) void attn(const u16* __restrict__ Qb, const u16* __restrict__ Kr,
                                              const u16* __restrict__ Vr, u16* __restrict__ Mg){
  __shared__ u16 Ks[2][8192];
  __shared__ u16 Vs[2][8192];
  const int fid = blockIdx.y * 8 + blockIdx.x;         // nwg = 256, %8 == 0
  const int o   = (fid & 7) * 32 + (fid >> 3);
  const int qt = o & 7, bh = o >> 3, b = bh >> 4, h = bh & 15;
  const int tid = threadIdx.x, lane = tid & 63, w = tid >> 6;
  const int quad = lane >> 4, lr = lane & 15;
  const int q0 = qt*256 + w*32;

  bf16x8 aq[2][2];   // [q-subtile][ks]; Q pre-scaled by CL2
  #pragma unroll
  for (int t=0;t<2;t++)
    #pragma unroll
    for (int ks=0;ks<2;ks++)
      aq[t][ks] = *(const bf16x8*)(Qb + (size_t)(b*2048 + q0 + t*16 + lr)*1024 + h*64 + ks*32 + quad*8);

  f32x4 acco[2][4] = {};
  f32x4 accl[2] = {};
  const bf16x8 ones8 = {(short)0x3F80,(short)0x3F80,(short)0x3F80,(short)0x3F80,
                        (short)0x3F80,(short)0x3F80,(short)0x3F80,(short)0x3F80};

  const u16* Krb = Kr + (size_t)bh*131072;   // 16 kv-blocks * 8192 elems
  const u16* Vrb = Vr + (size_t)bh*131072;

  // prefetch kv-block 0 (2 chunks of 8 KB each per buffer; 512 thr x 16 B)
  #pragma unroll
  for (int j=0;j<2;j++){
    gld_lds16(Krb + j*4096 + tid*8, &Ks[0][j*4096 + w*512]);
    gld_lds16(Vrb + j*4096 + tid*8, &Vs[0][j*4096 + w*512]);
  }

  for (int kb = 0; kb < 16; kb++){
    __syncthreads();                       // staged data for kb now visible
    const int cur = kb & 1;
    if (kb < 15){
      const u16* kg = Krb + (size_t)(kb+1)*8192;
      const u16* vg = Vrb + (size_t)(kb+1)*8192;
      #pragma unroll
      for (int j=0;j<2;j++){
        gld_lds16(kg + j*4096 + tid*8, &Ks[cur^1][j*4096 + w*512]);
        gld_lds16(vg + j*4096 + tid*8, &Vs[cur^1][j*4096 + w*512]);
      }
    }
    const u16* Ksc = Ks[cur];
    const u16* Vsc = Vs[cur];

    // ---- per 32-kv pair of subtiles: QK -> exp/pack -> l -> PV, all native x32 ----
    #pragma unroll
    for (int mt2=0;mt2<4;mt2++){
      f32x4 ae0 = {}, ae1 = {}, ao0 = {}, ao1 = {};
      {
        bf16x8 kf0 = *(const bf16x8*)(Ksc + (0*4+quad)*1024 + ((2*mt2)*16+lr)*8);
        bf16x8 kf1 = *(const bf16x8*)(Ksc + (1*4+quad)*1024 + ((2*mt2)*16+lr)*8);
        ae0 = __builtin_amdgcn_mfma_f32_16x16x32_bf16(kf0, aq[0][0], ae0, 0,0,0);
        ae1 = __builtin_amdgcn_mfma_f32_16x16x32_bf16(kf0, aq[1][0], ae1, 0,0,0);
        ae0 = __builtin_amdgcn_mfma_f32_16x16x32_bf16(kf1, aq[0][1], ae0, 0,0,0);
        ae1 = __builtin_amdgcn_mfma_f32_16x16x32_bf16(kf1, aq[1][1], ae1, 0,0,0);
      }
      {
        bf16x8 kf0 = *(const bf16x8*)(Ksc + (0*4+quad)*1024 + ((2*mt2+1)*16+lr)*8);
        bf16x8 kf1 = *(const bf16x8*)(Ksc + (1*4+quad)*1024 + ((2*mt2+1)*16+lr)*8);
        ao0 = __builtin_amdgcn_mfma_f32_16x16x32_bf16(kf0, aq[0][0], ao0, 0,0,0);
        ao1 = __builtin_amdgcn_mfma_f32_16x16x32_bf16(kf0, aq[1][0], ao1, 0,0,0);
        ao0 = __builtin_amdgcn_mfma_f32_16x16x32_bf16(kf1, aq[0][1], ao0, 0,0,0);
        ao1 = __builtin_amdgcn_mfma_f32_16x16x32_bf16(kf1, aq[1][1], ao1, 0,0,0);
      }

      // p = exp2(s'); pack even-mt into elems 0..3, odd-mt into 4..7 (x32 B-frag order)
      union { int4 i4; bf16x8 v; } pf0, pf1;
      pf0.i4.x = pack_bf16(__builtin_amdgcn_exp2f(ae0[0]), __builtin_amdgcn_exp2f(ae0[1]));
      pf0.i4.y = pack_bf16(__builtin_amdgcn_exp2f(ae0[2]), __builtin_amdgcn_exp2f(ae0[3]));
      pf0.i4.z = pack_bf16(__builtin_amdgcn_exp2f(ao0[0]), __builtin_amdgcn_exp2f(ao0[1]));
      pf0.i4.w = pack_bf16(__builtin_amdgcn_exp2f(ao0[2]), __builtin_amdgcn_exp2f(ao0[3]));
      pf1.i4.x = pack_bf16(__builtin_amdgcn_exp2f(ae1[0]), __builtin_amdgcn_exp2f(ae1[1]));
      pf1.i4.y = pack_bf16(__builtin_amdgcn_exp2f(ae1[2]), __builtin_amdgcn_exp2f(ae1[3]));
      pf1.i4.z = pack_bf16(__builtin_amdgcn_exp2f(ao1[0]), __builtin_amdgcn_exp2f(ao1[1]));
      pf1.i4.w = pack_bf16(__builtin_amdgcn_exp2f(ao1[2]), __builtin_amdgcn_exp2f(ao1[3]));

      // l via native x32: every C row = sum over this 32-kv chunk
      accl[0] = __builtin_amdgcn_mfma_f32_16x16x32_bf16(ones8, pf0.v, accl[0], 0,0,0);
      accl[1] = __builtin_amdgcn_mfma_f32_16x16x32_bf16(ones8, pf1.v, accl[1], 0,0,0);

      // O^T += V^T * P^T (32 kv per op; vf read feeds both q-subtiles)
      #pragma unroll
      for (int dt=0;dt<4;dt++){
        bf16x8 vf = *(const bf16x8*)(Vsc + (mt2*4+quad)*512 + (dt*16+lr)*8);
        acco[0][dt] = __builtin_amdgcn_mfma_f32_16x16x32_bf16(vf, pf0.v, acco[0][dt], 0,0,0);
        acco[1][dt] = __builtin_amdgcn_mfma_f32_16x16x32_bf16(vf, pf1.v, acco[1][dt], 0,0,0);
      }
    }
  }

  // ---- epilogue: accl rows are all identical = l(q=lane&15); lane-local ----
  #pragma unroll
  for (int t=0;t<2;t++){
    float inv = 1.f / accl[t][0];
    u16* dst = Mg + (size_t)(b*2048 + q0 + t*16 + lr)*1024 + h*64;
    #pragma unroll
    for (int dt=0;dt<4;dt++){
      bf16x4 o2;
      #pragma unroll
      for (int rg=0;rg<4;rg++) o2[rg] = (short)f2bf(acco[t][dt][rg]*inv);
      *(bf16x4*)(dst + dt*16 + quad*4) = o2;
    }
  }
}

extern "C" void kernel_launch(void* const* d_in, const int* in_sizes, int n_in,
                              void* d_out, int out_size, void* d_ws, size_t ws_size,
                              hipStream_t stream){
  const float* q  = (const float*)d_in[0];
  const float* k  = (const float*)d_in[1];
  const float* v  = (const float*)d_in[2];
  const float* Wq = (const float*)d_in[3];
  const float* bq = (const float*)d_in[4];
  const float* Wk = (const float*)d_in[5];
  const float* bk = (const float*)d_in[6];
  const float* Wv = (const float*)d_in[7];
  const float* bv = (const float*)d_in[8];
  const float* Wo = (const float*)d_in[9];
  const float* bo = (const float*)d_in[10];
  const float* Wc = (const float*)d_in[11];
  const float* bc = (const float*)d_in[12];
  char* ws = (char*)d_ws;
  u16* qb  = (u16*)(ws + (size_t)0*MB);
  u16* kb  = (u16*)(ws + (size_t)8*MB);
  u16* vb  = (u16*)(ws + (size_t)16*MB);
  u16* Wqt = (u16*)(ws + (size_t)24*MB);
  u16* Wkt = (u16*)(ws + (size_t)26*MB);
  u16* Wvt = (u16*)(ws + (size_t)28*MB);
  u16* Wot = (u16*)(ws + (size_t)30*MB);
  u16* Wct = (u16*)(ws + (size_t)32*MB);
  u16* Qb  = (u16*)(ws + (size_t)34*MB);
  u16* Kr  = (u16*)(ws + (size_t)42*MB);
  u16* Vr  = (u16*)(ws + (size_t)50*MB);
  u16* Mg  = (u16*)(ws + (size_t)58*MB);

  dim3 blk(256,1,1);
  hipLaunchKernelGGL(conv_all, dim3(4096,1,4), blk, 0, stream,
                     q,k,v, qb,kb,vb, Wq,Wk,Wv,Wo,Wc, Wqt,Wkt,Wvt,Wot,Wct);
  hipLaunchKernelGGL(qkv_gemm, dim3(8,32,3),   blk, 0, stream, qb,kb,vb, Wqt,Wkt,Wvt, bq,bk,bv, Qb,Kr,Vr);
  hipLaunchKernelGGL(attn,     dim3(8,32,1),   dim3(512,1,1), 0, stream, Qb, Kr, Vr, Mg);
  hipLaunchKernelGGL(out_gemm, dim3(8,32,2),   blk, 0, stream, Mg, Wct, Wot, bc, bo, (float*)d_out);
}